// Round 1
// baseline (660.409 us; speedup 1.0000x reference)
//
#include <hip/hip_runtime.h>

#define N_BINS 15

// One wave handles 4 rows per iteration: 16 lanes per row, each lane owns
// 8 elements (two float4 loads: cols [4*gl,4*gl+4) and [64+4*gl,64+4*gl+4)).
// Per-instruction access: 4 groups x 16 lanes x 16B = four contiguous 256B
// segments (rows are 512B apart) -> fully coalesced.
__global__ __launch_bounds__(256) void ece_partial(
    const float* __restrict__ logits,
    const int* __restrict__ labels,
    float* __restrict__ gbins,   // [2*N_BINS]: conf sums then correct sums
    int n_rows)
{
    __shared__ float sbin[2 * N_BINS];
    const int tid = threadIdx.x;
    if (tid < 2 * N_BINS) sbin[tid] = 0.0f;
    __syncthreads();

    const int lane = tid & 63;
    const int wid  = tid >> 6;      // wave id within block (0..3)
    const int g    = lane >> 4;     // which of the wave's 4 rows
    const int gl   = lane & 15;     // lane within the 16-lane row group

    const int waves_in_grid = gridDim.x * 4;

    for (int base = (blockIdx.x * 4 + wid) * 4; base < n_rows;
         base += waves_in_grid * 4)
    {
        const int row = base + g;                 // n_rows % 4 == 0 (1e6)
        const size_t roff = (size_t)row * 128;
        const float4 a = *reinterpret_cast<const float4*>(logits + roff + gl * 4);
        const float4 b = *reinterpret_cast<const float4*>(logits + roff + 64 + gl * 4);

        // ---- local max + first-occurrence argmax (strict > keeps first) ----
        float m = a.x; int mi = gl * 4;
        if (a.y > m) { m = a.y; mi = gl * 4 + 1; }
        if (a.z > m) { m = a.z; mi = gl * 4 + 2; }
        if (a.w > m) { m = a.w; mi = gl * 4 + 3; }
        if (b.x > m) { m = b.x; mi = 64 + gl * 4; }
        if (b.y > m) { m = b.y; mi = 64 + gl * 4 + 1; }
        if (b.z > m) { m = b.z; mi = 64 + gl * 4 + 2; }
        if (b.w > m) { m = b.w; mi = 64 + gl * 4 + 3; }

        // ---- butterfly (max, min-idx-on-tie) across the 16-lane group ----
        #pragma unroll
        for (int off = 1; off <= 8; off <<= 1) {
            float om = __shfl_xor(m, off);
            int   oi = __shfl_xor(mi, off);
            if (om > m || (om == m && oi < mi)) { m = om; mi = oi; }
        }

        // ---- sum of exp(v - m); exp(x) = exp2(x * log2e) -> native v_exp_f32
        const float L = 1.44269504088896340736f;
        const float nm = -m;
        float s = exp2f((a.x + nm) * L) + exp2f((a.y + nm) * L)
                + exp2f((a.z + nm) * L) + exp2f((a.w + nm) * L)
                + exp2f((b.x + nm) * L) + exp2f((b.y + nm) * L)
                + exp2f((b.z + nm) * L) + exp2f((b.w + nm) * L);
        #pragma unroll
        for (int off = 1; off <= 8; off <<= 1)
            s += __shfl_xor(s, off);

        // ---- one lane per row: confidence, bin, block-local accumulate ----
        if (gl == 0 && row < n_rows) {
            const float conf = 1.0f / s;          // max prob = exp(0)/sum
            const float acc  = (mi == labels[row]) ? 1.0f : 0.0f;
            int bin = (int)ceilf(conf * (float)N_BINS) - 1;
            bin = bin < 0 ? 0 : (bin > N_BINS - 1 ? N_BINS - 1 : bin);
            atomicAdd(&sbin[bin], conf);
            atomicAdd(&sbin[N_BINS + bin], acc);
        }
    }

    __syncthreads();
    if (tid < 2 * N_BINS) atomicAdd(&gbins[tid], sbin[tid]);
}

__global__ void ece_final(const float* __restrict__ gbins,
                          float* __restrict__ out, float inv_n)
{
    if (threadIdx.x == 0 && blockIdx.x == 0) {
        float e = 0.0f;
        #pragma unroll
        for (int i = 0; i < N_BINS; ++i)
            e += fabsf(gbins[i] - gbins[N_BINS + i]);
        out[0] = e * inv_n;
    }
}

extern "C" void kernel_launch(void* const* d_in, const int* in_sizes, int n_in,
                              void* d_out, int out_size, void* d_ws, size_t ws_size,
                              hipStream_t stream)
{
    const float* logits = (const float*)d_in[0];
    const int*   labels = (const int*)d_in[1];
    const int    n_rows = in_sizes[1];          // labels count == N
    float* gbins = (float*)d_ws;                // 2*N_BINS floats of scratch

    // d_ws is re-poisoned to 0xAA before every timed launch -> zero it here.
    hipMemsetAsync(gbins, 0, 2 * N_BINS * sizeof(float), stream);

    // Memory-bound: ~2048 blocks saturate HBM; grid-stride covers the rest.
    const int blocks = 2048;
    ece_partial<<<blocks, 256, 0, stream>>>(logits, labels, gbins, n_rows);
    ece_final<<<1, 64, 0, stream>>>(gbins, (float*)d_out,
                                    1.0f / (float)n_rows);
}